// Round 11
// baseline (636.229 us; speedup 1.0000x reference)
//
#include <hip/hip_runtime.h>
#include <hip/hip_bf16.h>

#define N_TOK 4096
#define D_MODEL 2048
#define NHEAD 16
#define DKH 128

typedef __attribute__((ext_vector_type(8))) short short8v;
typedef __attribute__((ext_vector_type(4))) float f32x4;
typedef __attribute__((ext_vector_type(8))) unsigned short ush8;

static __device__ __forceinline__ unsigned short f2bf(float f) {
  unsigned int x = __float_as_uint(f);
  return (unsigned short)((x + 0x7fffu + ((x >> 16) & 1u)) >> 16);
}
static __device__ __forceinline__ float bf2f(unsigned short u) {
  return __uint_as_float(((unsigned int)u) << 16);
}

// async global->LDS, 16B per lane (proj only)
static __device__ __forceinline__ void gld16(const void* g, void* l) {
  __builtin_amdgcn_global_load_lds(
      (const __attribute__((address_space(1))) unsigned int*)g,
      (__attribute__((address_space(3))) unsigned int*)l, 16, 0, 0);
}

// ---------------- Split kernels (unchanged) ------------------------------------
__global__ __launch_bounds__(256)
void split_e_kernel(const float* __restrict__ E,
                    unsigned short* __restrict__ Eh,
                    unsigned short* __restrict__ El) {
  const size_t i = ((size_t)blockIdx.x * 256 + threadIdx.x) * 8;
  const int n = (int)(i >> 11), d0 = (int)(i & 2047);
  float4 v0 = *reinterpret_cast<const float4*>(E + i);
  float4 v1 = *reinterpret_cast<const float4*>(E + i + 4);
  float f[8] = {v0.x, v0.y, v0.z, v0.w, v1.x, v1.y, v1.z, v1.w};
  ush8 hi, lo;
#pragma unroll
  for (int j = 0; j < 8; ++j) {
    unsigned short hu = f2bf(f[j]);
    hi[j] = hu;
    lo[j] = f2bf(f[j] - bf2f(hu));
  }
  const size_t off = (size_t)n * D_MODEL + (d0 ^ ((n & 7) << 3));
  *reinterpret_cast<ush8*>(Eh + off) = hi;
  *reinterpret_cast<ush8*>(El + off) = lo;
}

__global__ __launch_bounds__(256)
void split_w_kernel(const float* __restrict__ Wq, const float* __restrict__ Wk,
                    const float* __restrict__ Wv,
                    unsigned short* __restrict__ WTh,
                    unsigned short* __restrict__ WTl) {
  __shared__ float tile[64][65];
  const int t = threadIdx.x;
  const int d0 = blockIdx.x * 64;
  const int k0 = blockIdx.y * 64;
  const int mh = blockIdx.z;
  const int mat = mh >> 4, h = mh & 15;
  const float* W = (mat == 0) ? Wq : (mat == 1) ? Wk : Wv;
  const float* Wp = W + (size_t)h * D_MODEL * DKH;
  const float fac = (mat == 0) ? (1.44269504089f / sqrtf(128.0f)) : 1.0f;

  const int rr = t >> 4, c4 = (t & 15) * 4;
#pragma unroll
  for (int p = 0; p < 4; ++p) {
    float4 v = *reinterpret_cast<const float4*>(Wp + (size_t)(d0 + rr + 16 * p) * DKH + k0 + c4);
    tile[rr + 16 * p][c4 + 0] = v.x * fac;
    tile[rr + 16 * p][c4 + 1] = v.y * fac;
    tile[rr + 16 * p][c4 + 2] = v.z * fac;
    tile[rr + 16 * p][c4 + 3] = v.w * fac;
  }
  __syncthreads();
  const int dd0 = (t & 7) * 8, kl = t >> 3;
#pragma unroll
  for (int p = 0; p < 2; ++p) {
    const int kg = k0 + kl + 32 * p;
    ush8 hi, lo;
#pragma unroll
    for (int j = 0; j < 8; ++j) {
      float f = tile[dd0 + j][kl + 32 * p];
      unsigned short hu = f2bf(f);
      hi[j] = hu;
      lo[j] = f2bf(f - bf2f(hu));
    }
    const size_t base = ((size_t)(mat * NHEAD + h) * DKH + kg) * D_MODEL +
                        d0 + (dd0 ^ ((kg & 7) << 3));
    *reinterpret_cast<ush8*>(WTh + base) = hi;
    if (mat < 2) *reinterpret_cast<ush8*>(WTl + base) = lo;
  }
}

// ---------------- Projection GEMM (R4 version, incl. R4 V layout) --------------
template <int MODE>
__global__ __launch_bounds__(256, 2)
void proj_gemm_kernel(const unsigned short* __restrict__ Eh,
                      const unsigned short* __restrict__ El,
                      const unsigned short* __restrict__ WTh,
                      const unsigned short* __restrict__ WTl,
                      unsigned short* __restrict__ Qhi, unsigned short* __restrict__ Qlo,
                      unsigned short* __restrict__ Khi, unsigned short* __restrict__ Klo,
                      unsigned short* __restrict__ Vt, int h0) {
  __shared__ alignas(16) unsigned short Ah[128 * 64];
  __shared__ alignas(16) unsigned short Bh[128 * 64];
  __shared__ alignas(16) unsigned short Al[MODE == 0 ? 128 * 64 : 16];
  __shared__ alignas(16) unsigned short Bl[MODE == 0 ? 128 * 64 : 16];

  const int t = threadIdx.x;
  const int nb = blockIdx.x, hl = blockIdx.y, h = h0 + hl;
  const int mat = (MODE == 0) ? blockIdx.z : 2;
  const int wv = t >> 6, lane = t & 63, fr = lane & 15, fq = lane >> 4;
  const int m0 = (wv >> 1) * 64, n0 = (wv & 1) * 64;

  const char *pAh, *pBh, *pAl = nullptr, *pBl = nullptr;
  if (MODE == 0) {
    pAh = (const char*)(Eh + (size_t)nb * 128 * D_MODEL);
    pAl = (const char*)(El + (size_t)nb * 128 * D_MODEL);
    pBh = (const char*)(WTh + ((size_t)mat * NHEAD + h) * DKH * D_MODEL);
    pBl = (const char*)(WTl + ((size_t)mat * NHEAD + h) * DKH * D_MODEL);
  } else {
    pAh = (const char*)(WTh + ((size_t)2 * NHEAD + h) * DKH * D_MODEL);
    pBh = (const char*)(Eh + (size_t)nb * 128 * D_MODEL);
  }

  f32x4 acc[4][4];
#pragma unroll
  for (int a = 0; a < 4; ++a)
#pragma unroll
    for (int b = 0; b < 4; ++b) acc[a][b] = f32x4{0.f, 0.f, 0.f, 0.f};

  for (int d0 = 0; d0 < D_MODEL; d0 += 64) {
    __syncthreads();
    {
      const size_t gb = (size_t)d0 * 2 + (size_t)(t >> 3) * 4096 + (t & 7) * 16;
#pragma unroll
      for (int j = 0; j < 4; ++j) {
        gld16(pAh + gb + (size_t)j * 32 * 4096, (char*)Ah + j * 4096 + t * 16);
        gld16(pBh + gb + (size_t)j * 32 * 4096, (char*)Bh + j * 4096 + t * 16);
      }
      if (MODE == 0) {
#pragma unroll
        for (int j = 0; j < 4; ++j) {
          gld16(pAl + gb + (size_t)j * 32 * 4096, (char*)Al + j * 4096 + t * 16);
          gld16(pBl + gb + (size_t)j * 32 * 4096, (char*)Bl + j * 4096 + t * 16);
        }
      }
    }
    __syncthreads();
    __builtin_amdgcn_s_setprio(1);
#pragma unroll
    for (int ks = 0; ks < 2; ++ks) {
      short8v ah[4], al[4];
#pragma unroll
      for (int mi = 0; mi < 4; ++mi) {
        const int r = m0 + 16 * mi + fr;
        const int off = (ks * 32 + fq * 8) ^ ((r & 7) << 3);
        ah[mi] = *reinterpret_cast<const short8v*>(&Ah[r * 64 + off]);
        if (MODE == 0) al[mi] = *reinterpret_cast<const short8v*>(&Al[r * 64 + off]);
      }
#pragma unroll
      for (int ni = 0; ni < 4; ++ni) {
        const int rn = n0 + 16 * ni + fr;
        const int offn = (ks * 32 + fq * 8) ^ ((rn & 7) << 3);
        short8v bh = *reinterpret_cast<const short8v*>(&Bh[rn * 64 + offn]);
        if (MODE == 0) {
          short8v bl = *reinterpret_cast<const short8v*>(&Bl[rn * 64 + offn]);
#pragma unroll
          for (int mi = 0; mi < 4; ++mi) {
            acc[mi][ni] = __builtin_amdgcn_mfma_f32_16x16x32_bf16(ah[mi], bh, acc[mi][ni], 0, 0, 0);
            acc[mi][ni] = __builtin_amdgcn_mfma_f32_16x16x32_bf16(ah[mi], bl, acc[mi][ni], 0, 0, 0);
            acc[mi][ni] = __builtin_amdgcn_mfma_f32_16x16x32_bf16(al[mi], bh, acc[mi][ni], 0, 0, 0);
          }
        } else {
#pragma unroll
          for (int mi = 0; mi < 4; ++mi)
            acc[mi][ni] = __builtin_amdgcn_mfma_f32_16x16x32_bf16(ah[mi], bh, acc[mi][ni], 0, 0, 0);
        }
      }
    }
    __builtin_amdgcn_s_setprio(0);
  }

  if (MODE == 0) {
    unsigned short* Ohi = (mat == 0) ? Qhi : Khi;
    unsigned short* Olo = (mat == 0) ? Qlo : Klo;
#pragma unroll
    for (int mi = 0; mi < 4; ++mi)
#pragma unroll
      for (int ni = 0; ni < 4; ++ni)
#pragma unroll
        for (int i = 0; i < 4; ++i) {
          float v = acc[mi][ni][i];
          unsigned short hu = f2bf(v);
          unsigned short lu = f2bf(v - bf2f(hu));
          int n = nb * 128 + m0 + 16 * mi + fq * 4 + i;
          int k = n0 + 16 * ni + fr;
          if (mat == 1) k ^= ((n & 7) << 3);
          size_t off = ((size_t)hl * N_TOK + n) * DKH + k;
          Ohi[off] = hu;
          Olo[off] = lu;
        }
  } else {
    // R4 V layout: Vt[hl][DKH][N_TOK], per-64-key column swizzle for attn reads
#pragma unroll
    for (int mi = 0; mi < 4; ++mi)
#pragma unroll
      for (int ni = 0; ni < 4; ++ni)
#pragma unroll
        for (int i = 0; i < 4; ++i) {
          int kout = m0 + 16 * mi + fq * 4 + i;
          int tn = nb * 128 + n0 + 16 * ni + fr;
          int ts = (tn & ~63) | ((tn & 63) ^ ((kout & 7) << 3));
          Vt[((size_t)hl * DKH + kout) * N_TOK + ts] = f2bf(acc[mi][ni][i]);
        }
  }
}

// ---------------- Flash attention (R4 kernel + T14 async-stage split) ----------
// Identical math to the 330us R4 kernel. Staging changed from global_load_lds
// to reg-staged: loads for tile t+1 issue BEFORE compute(t) (sched_barrier-
// pinned), ds_write lands after the barrier -> L2 latency hides under compute.
// (256,1): T14 regs push VGPR past the 256/N=128 cap of (256,2); grid caps
// occupancy at 2 blocks/CU regardless, so VGPR up to 256 is free.
__global__ __launch_bounds__(256, 1)
void attn_kernel(const unsigned short* __restrict__ Qhi,
                 const unsigned short* __restrict__ Qlo,
                 const unsigned short* __restrict__ Khi,
                 const unsigned short* __restrict__ Klo,
                 const unsigned short* __restrict__ Vt,
                 float* __restrict__ out, int h0, int HC)
{
  __shared__ alignas(16) unsigned short KhiL[64][128];
  __shared__ alignas(16) unsigned short KloL[64][128];
  __shared__ alignas(16) unsigned short VtL[128][64];
  __shared__ unsigned int PL32[4][2][32][20];   // [wave][m][key/2][q], pad 20

  const int t = threadIdx.x;
  int b = blockIdx.x;
  const int nwg = 32 * HC;
  if ((nwg & 7) == 0) b = (b & 7) * (nwg >> 3) + (b >> 3);
  const int qb = b & 31;
  const int hl = b >> 5;
  const int h  = h0 + hl;
  const int wv = t >> 6, lane = t & 63;
  const int fr = lane & 15, fq = lane >> 4;
  const int q0 = qb * 128 + wv * 32;

  // Q fragments (hi/lo) as MFMA B-operand: q-index = fr
  short8v qhi[2][4], qlo[2][4];
#pragma unroll
  for (int m = 0; m < 2; ++m) {
    const unsigned short* qp  = Qhi + ((size_t)hl * N_TOK + q0 + m * 16 + fr) * DKH + fq * 8;
    const unsigned short* qp2 = Qlo + ((size_t)hl * N_TOK + q0 + m * 16 + fr) * DKH + fq * 8;
#pragma unroll
    for (int kc = 0; kc < 4; ++kc) {
      qhi[m][kc] = *reinterpret_cast<const short8v*>(qp + kc * 32);
      qlo[m][kc] = *reinterpret_cast<const short8v*>(qp2 + kc * 32);
    }
  }

  f32x4 o[2][8];   // O^T: o[m][of][i] = dk (of*16+fq*4+i), q = m*16+fr
#pragma unroll
  for (int m = 0; m < 2; ++m)
#pragma unroll
    for (int i = 0; i < 8; ++i) o[m][i] = f32x4{0.f, 0.f, 0.f, 0.f};
  float mrow[2] = {-__builtin_inff(), -__builtin_inff()};
  float lrow[2] = {0.f, 0.f};

  const char* KhiB = (const char*)(Khi + (size_t)hl * N_TOK * DKH);
  const char* KloB = (const char*)(Klo + (size_t)hl * N_TOK * DKH);
  const char* VtB  = (const char*)(Vt  + (size_t)hl * DKH * N_TOK);
  const int toff = t * 16;
  const int vrow = t >> 3, vbyte = (t & 7) * 16;

  // T14 prefetch registers (12 x 16B = 48 VGPR)
  ush8 kh_r[4], kl_r[4], vv_r[4];
  auto load_regs = [&](int kt) {
    const int key0 = kt * 64;
    const char* gk  = KhiB + (size_t)key0 * 256;
    const char* gk2 = KloB + (size_t)key0 * 256;
#pragma unroll
    for (int j = 0; j < 4; ++j) {
      kh_r[j] = *reinterpret_cast<const ush8*>(gk  + j * 4096 + toff);
      kl_r[j] = *reinterpret_cast<const ush8*>(gk2 + j * 4096 + toff);
      vv_r[j] = *reinterpret_cast<const ush8*>(
          VtB + (size_t)(j * 32 + vrow) * (N_TOK * 2) + key0 * 2 + vbyte);
    }
  };
  auto write_lds = [&]() {
#pragma unroll
    for (int j = 0; j < 4; ++j) {
      *reinterpret_cast<ush8*>((char*)&KhiL[0][0] + j * 4096 + toff) = kh_r[j];
      *reinterpret_cast<ush8*>((char*)&KloL[0][0] + j * 4096 + toff) = kl_r[j];
      *reinterpret_cast<ush8*>((char*)&VtL[0][0]  + j * 4096 + toff) = vv_r[j];
    }
  };

  load_regs(0);
  for (int kt = 0; kt < N_TOK / 64; ++kt) {
    __syncthreads();                 // previous tile's LDS reads complete
    write_lds();                     // compiler waits vmcnt for reg deps
    if (kt + 1 < N_TOK / 64) load_regs(kt + 1);   // prefetch next tile
    __builtin_amdgcn_sched_barrier(0);            // pin loads before barrier
    __syncthreads();                 // writes visible to all waves

    // T = K Q^T (3-term fp32 emulation), kc-outer for 8-chain ILP
    f32x4 tt[2][4];
#pragma unroll
    for (int m = 0; m < 2; ++m)
#pragma unroll
      for (int kf = 0; kf < 4; ++kf) tt[m][kf] = f32x4{0.f, 0.f, 0.f, 0.f};
    __builtin_amdgcn_s_setprio(1);
#pragma unroll
    for (int kc = 0; kc < 4; ++kc) {
      short8v khf[4], klf[4];
#pragma unroll
      for (int kf = 0; kf < 4; ++kf) {
        const int kr = kf * 16 + fr;
        const int off = (kc * 32 + fq * 8) ^ ((kr & 7) << 3);
        khf[kf] = *reinterpret_cast<const short8v*>(&KhiL[kr][off]);
        klf[kf] = *reinterpret_cast<const short8v*>(&KloL[kr][off]);
      }
#pragma unroll
      for (int kf = 0; kf < 4; ++kf)
#pragma unroll
        for (int m = 0; m < 2; ++m) {
          tt[m][kf] = __builtin_amdgcn_mfma_f32_16x16x32_bf16(khf[kf], qhi[m][kc], tt[m][kf], 0, 0, 0);
          tt[m][kf] = __builtin_amdgcn_mfma_f32_16x16x32_bf16(klf[kf], qhi[m][kc], tt[m][kf], 0, 0, 0);
          tt[m][kf] = __builtin_amdgcn_mfma_f32_16x16x32_bf16(khf[kf], qlo[m][kc], tt[m][kf], 0, 0, 0);
        }
    }
    __builtin_amdgcn_s_setprio(0);

    // online softmax: per-lane scalar state for q = m*16 + fr
    float mx[2];
#pragma unroll
    for (int m = 0; m < 2; ++m) {
      float v = -__builtin_inff();
#pragma unroll
      for (int kf = 0; kf < 4; ++kf)
#pragma unroll
        for (int i = 0; i < 4; ++i) v = fmaxf(v, tt[m][kf][i]);
      v = fmaxf(v, __shfl_xor(v, 16));
      v = fmaxf(v, __shfl_xor(v, 32));
      mx[m] = v;
    }
    if (__any((mx[0] > mrow[0]) | (mx[1] > mrow[1]))) {
#pragma unroll
      for (int m = 0; m < 2; ++m) {
        float mn = fmaxf(mrow[m], mx[m]);
        float al = exp2f(mrow[m] - mn);
        mrow[m] = mn;
        lrow[m] *= al;
#pragma unroll
        for (int of = 0; of < 8; ++of)
#pragma unroll
          for (int i = 0; i < 4; ++i) o[m][of][i] *= al;
      }
    }
    // P = exp2(T - m) -> bf16 pairs -> PL32 rows = key/2 = kf*8 + 2*fq + hh
#pragma unroll
    for (int m = 0; m < 2; ++m) {
      float rs = 0.f;
#pragma unroll
      for (int kf = 0; kf < 4; ++kf)
#pragma unroll
        for (int hh = 0; hh < 2; ++hh) {
          float p0 = exp2f(tt[m][kf][2 * hh]     - mrow[m]);
          float p1 = exp2f(tt[m][kf][2 * hh + 1] - mrow[m]);
          unsigned short b0 = f2bf(p0), b1 = f2bf(p1);
          rs += bf2f(b0) + bf2f(b1);   // sum rounded P for exact normalization
          PL32[wv][m][kf * 8 + 2 * fq + hh][fr] = (unsigned)b0 | ((unsigned)b1 << 16);
        }
      rs += __shfl_xor(rs, 16);
      rs += __shfl_xor(rs, 32);
      lrow[m] += rs;
    }
    asm volatile("s_waitcnt lgkmcnt(0)" ::: "memory");
    __builtin_amdgcn_sched_barrier(0);

    // O^T += V^T P : A = VtL fragment (dk rows), B = P from PL32
    __builtin_amdgcn_s_setprio(1);
#pragma unroll
    for (int ks = 0; ks < 2; ++ks) {
      union { unsigned u[4]; short8v v; } pb[2];
#pragma unroll
      for (int m = 0; m < 2; ++m)
#pragma unroll
        for (int w = 0; w < 4; ++w)
          pb[m].u[w] = PL32[wv][m][16 * ks + 4 * fq + w][fr];
#pragma unroll
      for (int of = 0; of < 8; ++of) {
        const int dr = of * 16 + fr;
        short8v av = *reinterpret_cast<const short8v*>(
            &VtL[dr][(ks * 32 + fq * 8) ^ ((dr & 7) << 3)]);
#pragma unroll
        for (int m = 0; m < 2; ++m)
          o[m][of] = __builtin_amdgcn_mfma_f32_16x16x32_bf16(av, pb[m].v, o[m][of], 0, 0, 0);
      }
    }
    __builtin_amdgcn_s_setprio(0);
  }

  // epilogue: normalize, float4 stores (dk contiguous per lane)
#pragma unroll
  for (int m = 0; m < 2; ++m) {
    float inv = 1.0f / lrow[m];
    int n = q0 + m * 16 + fr;
    float* op = out + (size_t)n * (NHEAD * DKH) + h * DKH + fq * 4;
#pragma unroll
    for (int of = 0; of < 8; ++of) {
      float4 r = make_float4(o[m][of][0] * inv, o[m][of][1] * inv,
                             o[m][of][2] * inv, o[m][of][3] * inv);
      *reinterpret_cast<float4*>(op + of * 16) = r;
    }
  }
}

// ---------------- host launch --------------------------------------------------
extern "C" void kernel_launch(void* const* d_in, const int* in_sizes, int n_in,
                              void* d_out, int out_size, void* d_ws, size_t ws_size,
                              hipStream_t stream) {
  (void)in_sizes; (void)n_in; (void)out_size;
  const float* E  = (const float*)d_in[0];
  const float* Wq = (const float*)d_in[1];
  const float* Wk = (const float*)d_in[2];
  const float* Wv = (const float*)d_in[3];
  float* out = (float*)d_out;

  const size_t ND   = (size_t)N_TOK * D_MODEL;
  const size_t WThE = (size_t)3 * NHEAD * DKH * D_MODEL;
  const size_t WTlE = (size_t)2 * NHEAD * DKH * D_MODEL;
  const size_t phe  = (size_t)N_TOK * DKH;
  const size_t baseE = 2 * ND + WThE + WTlE;

  unsigned short* Eh  = (unsigned short*)d_ws;
  unsigned short* El  = Eh + ND;
  unsigned short* WTh = El + ND;
  unsigned short* WTl = WTh + WThE;
  unsigned short* chunk = WTl + WTlE;

  int HC = NHEAD;
  while (HC > 1 && (baseE + (size_t)HC * 5 * phe) * 2 > ws_size) HC >>= 1;

  split_e_kernel<<<dim3((unsigned)(ND / 8 / 256)), 256, 0, stream>>>(E, Eh, El);
  split_w_kernel<<<dim3(32, 2, 48), 256, 0, stream>>>(Wq, Wk, Wv, WTh, WTl);

  for (int h0 = 0; h0 < NHEAD; h0 += HC) {
    unsigned short* Qhi = chunk;
    unsigned short* Qlo = Qhi + (size_t)HC * phe;
    unsigned short* Khi = Qlo + (size_t)HC * phe;
    unsigned short* Klo = Khi + (size_t)HC * phe;
    unsigned short* Vt  = Klo + (size_t)HC * phe;
    // V first so K/V (attn's streamed operands) are L2-warmest at attn launch
    proj_gemm_kernel<1><<<dim3(32, HC, 1), 256, 0, stream>>>(Eh, El, WTh, WTl,
                                                             Qhi, Qlo, Khi, Klo, Vt, h0);
    proj_gemm_kernel<0><<<dim3(32, HC, 2), 256, 0, stream>>>(Eh, El, WTh, WTl,
                                                             Qhi, Qlo, Khi, Klo, Vt, h0);
    attn_kernel<<<dim3(32 * HC), 256, 0, stream>>>(Qhi, Qlo, Khi, Klo, Vt, out, h0, HC);
  }
}

// Round 12
// 498.150 us; speedup vs baseline: 1.2772x; 1.2772x over previous
//
#include <hip/hip_runtime.h>
#include <hip/hip_bf16.h>

#define N_TOK 4096
#define D_MODEL 2048
#define NHEAD 16
#define DKH 128

typedef __attribute__((ext_vector_type(8))) short short8v;
typedef __attribute__((ext_vector_type(4))) float f32x4;
typedef __attribute__((ext_vector_type(8))) unsigned short ush8;

static __device__ __forceinline__ unsigned short f2bf(float f) {
  unsigned int x = __float_as_uint(f);
  return (unsigned short)((x + 0x7fffu + ((x >> 16) & 1u)) >> 16);
}
static __device__ __forceinline__ float bf2f(unsigned short u) {
  return __uint_as_float(((unsigned int)u) << 16);
}

// async global->LDS, 16B per lane; LDS dest must be wave-uniform-base + lane*16
static __device__ __forceinline__ void gld16(const void* g, void* l) {
  __builtin_amdgcn_global_load_lds(
      (const __attribute__((address_space(1))) unsigned int*)g,
      (__attribute__((address_space(3))) unsigned int*)l, 16, 0, 0);
}

// ---------------- Split kernels (memory-bound, run once) -----------------------
__global__ __launch_bounds__(256)
void split_e_kernel(const float* __restrict__ E,
                    unsigned short* __restrict__ Eh,
                    unsigned short* __restrict__ El) {
  const size_t i = ((size_t)blockIdx.x * 256 + threadIdx.x) * 8;
  const int n = (int)(i >> 11), d0 = (int)(i & 2047);
  float4 v0 = *reinterpret_cast<const float4*>(E + i);
  float4 v1 = *reinterpret_cast<const float4*>(E + i + 4);
  float f[8] = {v0.x, v0.y, v0.z, v0.w, v1.x, v1.y, v1.z, v1.w};
  ush8 hi, lo;
#pragma unroll
  for (int j = 0; j < 8; ++j) {
    unsigned short hu = f2bf(f[j]);
    hi[j] = hu;
    lo[j] = f2bf(f[j] - bf2f(hu));
  }
  const size_t off = (size_t)n * D_MODEL + (d0 ^ ((n & 7) << 3));
  *reinterpret_cast<ush8*>(Eh + off) = hi;
  *reinterpret_cast<ush8*>(El + off) = lo;
}

__global__ __launch_bounds__(256)
void split_w_kernel(const float* __restrict__ Wq, const float* __restrict__ Wk,
                    const float* __restrict__ Wv,
                    unsigned short* __restrict__ WTh,
                    unsigned short* __restrict__ WTl) {
  __shared__ float tile[64][65];
  const int t = threadIdx.x;
  const int d0 = blockIdx.x * 64;
  const int k0 = blockIdx.y * 64;
  const int mh = blockIdx.z;
  const int mat = mh >> 4, h = mh & 15;
  const float* W = (mat == 0) ? Wq : (mat == 1) ? Wk : Wv;
  const float* Wp = W + (size_t)h * D_MODEL * DKH;
  const float fac = (mat == 0) ? (1.44269504089f / sqrtf(128.0f)) : 1.0f;

  const int rr = t >> 4, c4 = (t & 15) * 4;
#pragma unroll
  for (int p = 0; p < 4; ++p) {
    float4 v = *reinterpret_cast<const float4*>(Wp + (size_t)(d0 + rr + 16 * p) * DKH + k0 + c4);
    tile[rr + 16 * p][c4 + 0] = v.x * fac;
    tile[rr + 16 * p][c4 + 1] = v.y * fac;
    tile[rr + 16 * p][c4 + 2] = v.z * fac;
    tile[rr + 16 * p][c4 + 3] = v.w * fac;
  }
  __syncthreads();
  const int dd0 = (t & 7) * 8, kl = t >> 3;
#pragma unroll
  for (int p = 0; p < 2; ++p) {
    const int kg = k0 + kl + 32 * p;
    ush8 hi, lo;
#pragma unroll
    for (int j = 0; j < 8; ++j) {
      float f = tile[dd0 + j][kl + 32 * p];
      unsigned short hu = f2bf(f);
      hi[j] = hu;
      lo[j] = f2bf(f - bf2f(hu));
    }
    const size_t base = ((size_t)(mat * NHEAD + h) * DKH + kg) * D_MODEL +
                        d0 + (dd0 ^ ((kg & 7) << 3));
    *reinterpret_cast<ush8*>(WTh + base) = hi;
    if (mat < 2) *reinterpret_cast<ush8*>(WTl + base) = lo;
  }
}

// ---------------- Projection GEMM (gload_lds + swizzled LDS) -------------------
template <int MODE>
__global__ __launch_bounds__(256, 2)
void proj_gemm_kernel(const unsigned short* __restrict__ Eh,
                      const unsigned short* __restrict__ El,
                      const unsigned short* __restrict__ WTh,
                      const unsigned short* __restrict__ WTl,
                      unsigned short* __restrict__ Qhi, unsigned short* __restrict__ Qlo,
                      unsigned short* __restrict__ Khi, unsigned short* __restrict__ Klo,
                      unsigned short* __restrict__ Vt, int h0) {
  __shared__ alignas(16) unsigned short Ah[128 * 64];
  __shared__ alignas(16) unsigned short Bh[128 * 64];
  __shared__ alignas(16) unsigned short Al[MODE == 0 ? 128 * 64 : 16];
  __shared__ alignas(16) unsigned short Bl[MODE == 0 ? 128 * 64 : 16];

  const int t = threadIdx.x;
  const int nb = blockIdx.x, hl = blockIdx.y, h = h0 + hl;
  const int mat = (MODE == 0) ? blockIdx.z : 2;
  const int wv = t >> 6, lane = t & 63, fr = lane & 15, fq = lane >> 4;
  const int m0 = (wv >> 1) * 64, n0 = (wv & 1) * 64;

  const char *pAh, *pBh, *pAl = nullptr, *pBl = nullptr;
  if (MODE == 0) {
    pAh = (const char*)(Eh + (size_t)nb * 128 * D_MODEL);
    pAl = (const char*)(El + (size_t)nb * 128 * D_MODEL);
    pBh = (const char*)(WTh + ((size_t)mat * NHEAD + h) * DKH * D_MODEL);
    pBl = (const char*)(WTl + ((size_t)mat * NHEAD + h) * DKH * D_MODEL);
  } else {
    pAh = (const char*)(WTh + ((size_t)2 * NHEAD + h) * DKH * D_MODEL);
    pBh = (const char*)(Eh + (size_t)nb * 128 * D_MODEL);
  }

  f32x4 acc[4][4];
#pragma unroll
  for (int a = 0; a < 4; ++a)
#pragma unroll
    for (int b = 0; b < 4; ++b) acc[a][b] = f32x4{0.f, 0.f, 0.f, 0.f};

  for (int d0 = 0; d0 < D_MODEL; d0 += 64) {
    __syncthreads();
    {
      const size_t gb = (size_t)d0 * 2 + (size_t)(t >> 3) * 4096 + (t & 7) * 16;
#pragma unroll
      for (int j = 0; j < 4; ++j) {
        gld16(pAh + gb + (size_t)j * 32 * 4096, (char*)Ah + j * 4096 + t * 16);
        gld16(pBh + gb + (size_t)j * 32 * 4096, (char*)Bh + j * 4096 + t * 16);
      }
      if (MODE == 0) {
#pragma unroll
        for (int j = 0; j < 4; ++j) {
          gld16(pAl + gb + (size_t)j * 32 * 4096, (char*)Al + j * 4096 + t * 16);
          gld16(pBl + gb + (size_t)j * 32 * 4096, (char*)Bl + j * 4096 + t * 16);
        }
      }
    }
    __syncthreads();
    __builtin_amdgcn_s_setprio(1);
#pragma unroll
    for (int ks = 0; ks < 2; ++ks) {
      short8v ah[4], al[4];
#pragma unroll
      for (int mi = 0; mi < 4; ++mi) {
        const int r = m0 + 16 * mi + fr;
        const int off = (ks * 32 + fq * 8) ^ ((r & 7) << 3);
        ah[mi] = *reinterpret_cast<const short8v*>(&Ah[r * 64 + off]);
        if (MODE == 0) al[mi] = *reinterpret_cast<const short8v*>(&Al[r * 64 + off]);
      }
#pragma unroll
      for (int ni = 0; ni < 4; ++ni) {
        const int rn = n0 + 16 * ni + fr;
        const int offn = (ks * 32 + fq * 8) ^ ((rn & 7) << 3);
        short8v bh = *reinterpret_cast<const short8v*>(&Bh[rn * 64 + offn]);
        if (MODE == 0) {
          short8v bl = *reinterpret_cast<const short8v*>(&Bl[rn * 64 + offn]);
#pragma unroll
          for (int mi = 0; mi < 4; ++mi) {
            acc[mi][ni] = __builtin_amdgcn_mfma_f32_16x16x32_bf16(ah[mi], bh, acc[mi][ni], 0, 0, 0);
            acc[mi][ni] = __builtin_amdgcn_mfma_f32_16x16x32_bf16(ah[mi], bl, acc[mi][ni], 0, 0, 0);
            acc[mi][ni] = __builtin_amdgcn_mfma_f32_16x16x32_bf16(al[mi], bh, acc[mi][ni], 0, 0, 0);
          }
        } else {
#pragma unroll
          for (int mi = 0; mi < 4; ++mi)
            acc[mi][ni] = __builtin_amdgcn_mfma_f32_16x16x32_bf16(ah[mi], bh, acc[mi][ni], 0, 0, 0);
        }
      }
    }
    __builtin_amdgcn_s_setprio(0);
  }

  if (MODE == 0) {
    unsigned short* Ohi = (mat == 0) ? Qhi : Khi;
    unsigned short* Olo = (mat == 0) ? Qlo : Klo;
#pragma unroll
    for (int mi = 0; mi < 4; ++mi)
#pragma unroll
      for (int ni = 0; ni < 4; ++ni)
#pragma unroll
        for (int i = 0; i < 4; ++i) {
          float v = acc[mi][ni][i];
          unsigned short hu = f2bf(v);
          unsigned short lu = f2bf(v - bf2f(hu));
          int n = nb * 128 + m0 + 16 * mi + fq * 4 + i;
          int k = n0 + 16 * ni + fr;
          if (mat == 1) k ^= ((n & 7) << 3);
          size_t off = ((size_t)hl * N_TOK + n) * DKH + k;
          Ohi[off] = hu;
          Olo[off] = lu;
        }
  } else {
#pragma unroll
    for (int mi = 0; mi < 4; ++mi)
#pragma unroll
      for (int ni = 0; ni < 4; ++ni)
#pragma unroll
        for (int i = 0; i < 4; ++i) {
          int kout = m0 + 16 * mi + fq * 4 + i;
          int tn = nb * 128 + n0 + 16 * ni + fr;
          int ts = (tn & ~63) | ((tn & 63) ^ ((kout & 7) << 3));
          Vt[((size_t)hl * DKH + kout) * N_TOK + ts] = f2bf(acc[mi][ni][i]);
        }
  }
}

// ---------------- Flash attention, operand-swapped (C[key][q]) -----------------
// QK^T computed as mfma(A=K, B=Q) -> T[key][q] with q = lane&15: softmax row
// reductions need only shfl_xor(16/32); m/l/rescale are per-lane scalars.
// P redistributes through a tiny padded u32 LDS buffer directly into the PV
// B-frag k-order; PV is mfma(A=V^T, B=P) -> O^T[dk][q], stored with float4.
__global__ __launch_bounds__(256, 2)
void attn_kernel(const unsigned short* __restrict__ Qhi,
                 const unsigned short* __restrict__ Qlo,
                 const unsigned short* __restrict__ Khi,
                 const unsigned short* __restrict__ Klo,
                 const unsigned short* __restrict__ Vt,
                 float* __restrict__ out, int h0, int HC)
{
  __shared__ alignas(16) unsigned short KhiL[64][128];
  __shared__ alignas(16) unsigned short KloL[64][128];
  __shared__ alignas(16) unsigned short VtL[128][64];
  __shared__ unsigned int PL32[4][2][32][20];   // [wave][m][key/2][q], pad 20 -> 2-way max

  const int t = threadIdx.x;
  int b = blockIdx.x;
  const int nwg = 32 * HC;
  if ((nwg & 7) == 0) b = (b & 7) * (nwg >> 3) + (b >> 3);
  const int qb = b & 31;
  const int hl = b >> 5;
  const int h  = h0 + hl;
  const int wv = t >> 6, lane = t & 63;
  const int fr = lane & 15, fq = lane >> 4;
  const int q0 = qb * 128 + wv * 32;

  // Q fragments (hi/lo) as MFMA B-operand: q-index = fr
  short8v qhi[2][4], qlo[2][4];
#pragma unroll
  for (int m = 0; m < 2; ++m) {
    const unsigned short* qp  = Qhi + ((size_t)hl * N_TOK + q0 + m * 16 + fr) * DKH + fq * 8;
    const unsigned short* qp2 = Qlo + ((size_t)hl * N_TOK + q0 + m * 16 + fr) * DKH + fq * 8;
#pragma unroll
    for (int kc = 0; kc < 4; ++kc) {
      qhi[m][kc] = *reinterpret_cast<const short8v*>(qp + kc * 32);
      qlo[m][kc] = *reinterpret_cast<const short8v*>(qp2 + kc * 32);
    }
  }

  f32x4 o[2][8];   // O^T: o[m][of][i] = dk (of*16+fq*4+i), q = m*16+fr
#pragma unroll
  for (int m = 0; m < 2; ++m)
#pragma unroll
    for (int i = 0; i < 8; ++i) o[m][i] = f32x4{0.f, 0.f, 0.f, 0.f};
  float mrow[2] = {-__builtin_inff(), -__builtin_inff()};
  float lrow[2] = {0.f, 0.f};

  const char* KhiB = (const char*)(Khi + (size_t)hl * N_TOK * DKH);
  const char* KloB = (const char*)(Klo + (size_t)hl * N_TOK * DKH);
  const char* VtB  = (const char*)(Vt  + (size_t)hl * DKH * N_TOK);
  const int toff = t * 16;
  const int vrow = t >> 1, vbyte = 0;   // unused placeholder kept minimal
  (void)vrow; (void)vbyte;
  const int vrow2 = t >> 3, vbyte2 = (t & 7) * 16;

  for (int kt = 0; kt < N_TOK / 64; ++kt) {
    const int key0 = kt * 64;
    __syncthreads();
    {
      const char* gk  = KhiB + (size_t)key0 * 256;
      const char* gk2 = KloB + (size_t)key0 * 256;
#pragma unroll
      for (int j = 0; j < 4; ++j)
        gld16(gk + j * 4096 + toff, (char*)&KhiL[0][0] + j * 4096 + toff);
#pragma unroll
      for (int j = 0; j < 4; ++j)
        gld16(gk2 + j * 4096 + toff, (char*)&KloL[0][0] + j * 4096 + toff);
#pragma unroll
      for (int j = 0; j < 4; ++j)
        gld16(VtB + (size_t)(j * 32 + vrow2) * (N_TOK * 2) + key0 * 2 + vbyte2,
              (char*)&VtL[0][0] + j * 4096 + toff);
    }
    __syncthreads();

    // T = K Q^T (3-term), kc-outer so 8 accumulator chains interleave (ILP)
    f32x4 tt[2][4];
#pragma unroll
    for (int m = 0; m < 2; ++m)
#pragma unroll
      for (int kf = 0; kf < 4; ++kf) tt[m][kf] = f32x4{0.f, 0.f, 0.f, 0.f};
    __builtin_amdgcn_s_setprio(1);
#pragma unroll
    for (int kc = 0; kc < 4; ++kc) {
      short8v khf[4], klf[4];
#pragma unroll
      for (int kf = 0; kf < 4; ++kf) {
        const int kr = kf * 16 + fr;
        const int off = (kc * 32 + fq * 8) ^ ((kr & 7) << 3);
        khf[kf] = *reinterpret_cast<const short8v*>(&KhiL[kr][off]);
        klf[kf] = *reinterpret_cast<const short8v*>(&KloL[kr][off]);
      }
#pragma unroll
      for (int kf = 0; kf < 4; ++kf)
#pragma unroll
        for (int m = 0; m < 2; ++m) {
          tt[m][kf] = __builtin_amdgcn_mfma_f32_16x16x32_bf16(khf[kf], qhi[m][kc], tt[m][kf], 0, 0, 0);
          tt[m][kf] = __builtin_amdgcn_mfma_f32_16x16x32_bf16(klf[kf], qhi[m][kc], tt[m][kf], 0, 0, 0);
          tt[m][kf] = __builtin_amdgcn_mfma_f32_16x16x32_bf16(khf[kf], qlo[m][kc], tt[m][kf], 0, 0, 0);
        }
    }
    __builtin_amdgcn_s_setprio(0);

    // online softmax: per-lane scalar state for q = m*16 + fr
    float mx[2];
#pragma unroll
    for (int m = 0; m < 2; ++m) {
      float v = -__builtin_inff();
#pragma unroll
      for (int kf = 0; kf < 4; ++kf)
#pragma unroll
        for (int i = 0; i < 4; ++i) v = fmaxf(v, tt[m][kf][i]);
      v = fmaxf(v, __shfl_xor(v, 16));
      v = fmaxf(v, __shfl_xor(v, 32));
      mx[m] = v;
    }
    if (__any((mx[0] > mrow[0]) | (mx[1] > mrow[1]))) {
#pragma unroll
      for (int m = 0; m < 2; ++m) {
        float mn = fmaxf(mrow[m], mx[m]);
        float al = exp2f(mrow[m] - mn);
        mrow[m] = mn;
        lrow[m] *= al;
#pragma unroll
        for (int of = 0; of < 8; ++of)
#pragma unroll
          for (int i = 0; i < 4; ++i) o[m][of][i] *= al;
      }
    }
    // P = exp2(T - m) -> bf16 pairs -> PL32 rows = key/2 = kf*8 + 2*fq + hh
#pragma unroll
    for (int m = 0; m < 2; ++m) {
      float rs = 0.f;
#pragma unroll
      for (int kf = 0; kf < 4; ++kf)
#pragma unroll
        for (int hh = 0; hh < 2; ++hh) {
          float p0 = exp2f(tt[m][kf][2 * hh]     - mrow[m]);
          float p1 = exp2f(tt[m][kf][2 * hh + 1] - mrow[m]);
          unsigned short b0 = f2bf(p0), b1 = f2bf(p1);
          rs += bf2f(b0) + bf2f(b1);   // sum rounded P for exact normalization
          PL32[wv][m][kf * 8 + 2 * fq + hh][fr] = (unsigned)b0 | ((unsigned)b1 << 16);
        }
      rs += __shfl_xor(rs, 16);
      rs += __shfl_xor(rs, 32);
      lrow[m] += rs;
    }
    asm volatile("s_waitcnt lgkmcnt(0)" ::: "memory");
    __builtin_amdgcn_sched_barrier(0);

    // O^T += V^T P : A = VtL fragment (dk rows), B = P from PL32
    __builtin_amdgcn_s_setprio(1);
#pragma unroll
    for (int ks = 0; ks < 2; ++ks) {
      union { unsigned u[4]; short8v v; } pb[2];
#pragma unroll
      for (int m = 0; m < 2; ++m)
#pragma unroll
        for (int w = 0; w < 4; ++w)
          pb[m].u[w] = PL32[wv][m][16 * ks + 4 * fq + w][fr];
#pragma unroll
      for (int of = 0; of < 8; ++of) {
        const int dr = of * 16 + fr;
        short8v av = *reinterpret_cast<const short8v*>(
            &VtL[dr][(ks * 32 + fq * 8) ^ ((dr & 7) << 3)]);
#pragma unroll
        for (int m = 0; m < 2; ++m)
          o[m][of] = __builtin_amdgcn_mfma_f32_16x16x32_bf16(av, pb[m].v, o[m][of], 0, 0, 0);
      }
    }
    __builtin_amdgcn_s_setprio(0);
  }

  // epilogue: normalize, float4 stores (dk contiguous per lane)
#pragma unroll
  for (int m = 0; m < 2; ++m) {
    float inv = 1.0f / lrow[m];
    int n = q0 + m * 16 + fr;
    float* op = out + (size_t)n * (NHEAD * DKH) + h * DKH + fq * 4;
#pragma unroll
    for (int of = 0; of < 8; ++of) {
      float4 r = make_float4(o[m][of][0] * inv, o[m][of][1] * inv,
                             o[m][of][2] * inv, o[m][of][3] * inv);
      *reinterpret_cast<float4*>(op + of * 16) = r;
    }
  }
}

// ---------------- host launch --------------------------------------------------
extern "C" void kernel_launch(void* const* d_in, const int* in_sizes, int n_in,
                              void* d_out, int out_size, void* d_ws, size_t ws_size,
                              hipStream_t stream) {
  (void)in_sizes; (void)n_in; (void)out_size;
  const float* E  = (const float*)d_in[0];
  const float* Wq = (const float*)d_in[1];
  const float* Wk = (const float*)d_in[2];
  const float* Wv = (const float*)d_in[3];
  float* out = (float*)d_out;

  const size_t ND   = (size_t)N_TOK * D_MODEL;
  const size_t WThE = (size_t)3 * NHEAD * DKH * D_MODEL;
  const size_t WTlE = (size_t)2 * NHEAD * DKH * D_MODEL;
  const size_t phe  = (size_t)N_TOK * DKH;
  const size_t baseE = 2 * ND + WThE + WTlE;

  unsigned short* Eh  = (unsigned short*)d_ws;
  unsigned short* El  = Eh + ND;
  unsigned short* WTh = El + ND;
  unsigned short* WTl = WTh + WThE;
  unsigned short* chunk = WTl + WTlE;

  int HC = NHEAD;
  while (HC > 1 && (baseE + (size_t)HC * 5 * phe) * 2 > ws_size) HC >>= 1;

  split_e_kernel<<<dim3((unsigned)(ND / 8 / 256)), 256, 0, stream>>>(E, Eh, El);
  split_w_kernel<<<dim3(32, 2, 48), 256, 0, stream>>>(Wq, Wk, Wv, WTh, WTl);

  for (int h0 = 0; h0 < NHEAD; h0 += HC) {
    unsigned short* Qhi = chunk;
    unsigned short* Qlo = Qhi + (size_t)HC * phe;
    unsigned short* Khi = Qlo + (size_t)HC * phe;
    unsigned short* Klo = Khi + (size_t)HC * phe;
    unsigned short* Vt  = Klo + (size_t)HC * phe;
    // V first so K/V (attn's streamed operands) are L2-warmest at attn launch
    proj_gemm_kernel<1><<<dim3(32, HC, 1), 256, 0, stream>>>(Eh, El, WTh, WTl,
                                                             Qhi, Qlo, Khi, Klo, Vt, h0);
    proj_gemm_kernel<0><<<dim3(32, HC, 2), 256, 0, stream>>>(Eh, El, WTh, WTl,
                                                             Qhi, Qlo, Khi, Klo, Vt, h0);
    attn_kernel<<<dim3(32 * HC), 256, 0, stream>>>(Qhi, Qlo, Khi, Klo, Vt, out, h0, HC);
  }
}